// Round 12
// baseline (296.874 us; speedup 1.0000x reference)
//
#include <hip/hip_runtime.h>

#define NS 5      // symbols
#define NW 33     // subcarriers
#define NA 16     // antennas
#define SW 165    // NS*NW
#define BUFS 99   // per-matrix LDS buffer (f2): x rows chunk (<=99), then T2 (99)
#define NFR 17    // Fsub rows stored (0..16; symmetry + conj-mirror covers rest)
#define SFS (NFR*NW)   // 561
#define MPW 5     // matrices per wave
#define GM 20     // matrices per block
#define TPM 11    // threads per matrix
#define CPT 3     // columns per thread
#define THREADS 256

// t-row chunks: chunk0 = t{0,1,2} full rows, chunk1 = t{3,4} full rows.
#define C0T 3
#define C0E (C0T*NW*MPW)   // 495
#define IT0 8
#define C1T 2
#define C1E (C1T*NW*MPW)   // 330
#define IT1 6

// R21: Good-Thomas DFT-33 = DFT-3 x DFT-11 for stage A. Input map
// w = (22*w3 + 12*w11) mod 33 makes the kernel twiddle-free:
// w33^(w*v) = w3^(2v*w3) * w11^(4v*w11). Thread j computes DFT-11 bin j per
// (t, w3) [coeffs w11^(jb)/sqrt33 = sFsub[3][(jb)%11], 5 regs, conj-paired],
// then an in-register radix-3 (w3 = -1/2 - i*sqrt3/2, raw) gives its 3
// columns Q[k] = (3j + 11k) mod 33. 70 pk-ops/lane/t vs 131 direct; Fsub
// row-reads (816 B/lane) collapse to 5 held regs. Stage E stays direct-paired
// (no FFT gain at 3 rows/thread); only T2/E/output indices take Q[k].
// arg5 for the register headroom (R17/R19: 48-reg budget clean; arg6's ~40
// would spill the +16 live) -- R20 proved occupancy 41->55% was worth only
// 2us, the FLOP cut is worth more. Kept: 17-row sFsub (R18), conj-pair
// E/C (R16), pk_fma (R11), wave-autonomy (R10), LDS staging (R12 lesson).
typedef float f2 __attribute__((ext_vector_type(2)));

// Good-Thomas input index table: W33[w3][b] = (22*w3 + 12*b) mod 33.
// Pairs (b, 11-b) are 33-complement-like within a w3 class (conj pairing).
constexpr int W33[3][11] = {
    { 0, 12, 24,  3, 15, 27,  6, 18, 30,  9, 21},
    {22,  1, 13, 25,  4, 16, 28,  7, 19, 31, 10},
    {11, 23,  2, 14, 26,  5, 17, 29,  8, 20, 32},
};

// z += u * Re(f):  (z.x += u.x*f.lo, z.y += u.y*f.lo)
__device__ __forceinline__ void cmac_re(f2& z, f2 u, f2 f) {
    asm("v_pk_fma_f32 %0, %1, %2, %0 op_sel:[0,0,0] op_sel_hi:[1,0,1]"
        : "+v"(z) : "v"(u), "v"(f));
}
// z += i * d * Im(f):  (z.x += -d.y*f.hi, z.y += d.x*f.hi)
__device__ __forceinline__ void cmac_im(f2& z, f2 d, f2 f) {
    asm("v_pk_fma_f32 %0, %1, %2, %0 op_sel:[1,1,0] op_sel_hi:[0,1,1] neg_lo:[1,0,0]"
        : "+v"(z) : "v"(d), "v"(f));
}
// z += conj(f) * P, P real pair Pp=(P,P): lo zr+=f.x*P, hi zi+=-f.y*P
__device__ __forceinline__ void cmacr(f2& z, f2 f, f2 Pp) {
    asm("v_pk_fma_f32 %0, %1, %2, %0 op_sel:[0,0,0] op_sel_hi:[1,1,1] neg_hi:[1,0,0]"
        : "+v"(z) : "v"(f), "v"(Pp));
}
// plain packed: z += a*b elementwise
__device__ __forceinline__ void pkfma(f2& z, f2 a, f2 b) {
    asm("v_pk_fma_f32 %0, %1, %2, %0 op_sel:[0,0,0] op_sel_hi:[1,1,1]"
        : "+v"(z) : "v"(a), "v"(b));
}
// r = a*b + c (3-operand packed fma)
__device__ __forceinline__ f2 pkfma3(f2 a, f2 b, f2 c) {
    f2 r; asm("v_pk_fma_f32 %0, %1, %2, %3 op_sel:[0,0,0] op_sel_hi:[1,1,1]"
              : "=v"(r) : "v"(a), "v"(b), "v"(c)); return r;
}
// r = a + b (packed)
__device__ __forceinline__ f2 pkadd(f2 a, f2 b) {
    f2 r; asm("v_pk_add_f32 %0, %1, %2" : "=v"(r) : "v"(a), "v"(b)); return r;
}
// r = a - b (packed)
__device__ __forceinline__ f2 pksub(f2 a, f2 b) {
    f2 r; asm("v_pk_add_f32 %0, %1, %2 neg_lo:[0,1] neg_hi:[0,1]"
              : "=v"(r) : "v"(a), "v"(b)); return r;
}
// r = (a.x + b.x, a.y - b.y)
__device__ __forceinline__ f2 pkaddsub(f2 a, f2 b) {
    f2 r; asm("v_pk_add_f32 %0, %1, %2 neg_hi:[0,1]"
              : "=v"(r) : "v"(a), "v"(b)); return r;
}
// r = u * Re(f) broadcast: (u.x*f.lo, u.y*f.lo)
__device__ __forceinline__ f2 pkmul_re(f2 u, f2 f) {
    f2 r; asm("v_pk_mul_f32 %0, %1, %2 op_sel:[0,0] op_sel_hi:[1,0]"
              : "=v"(r) : "v"(u), "v"(f)); return r;
}
// r = a * b elementwise
__device__ __forceinline__ f2 pkmul(f2 a, f2 b) {
    f2 r; asm("v_pk_mul_f32 %0, %1, %2" : "=v"(r) : "v"(a), "v"(b)); return r;
}
// r = i * s * d = (-s*d.y, s*d.x), s = ss.x = ss.y  (radix-3 imag part)
__device__ __forceinline__ f2 pkmul_i(f2 d, f2 ss) {
    f2 r; asm("v_pk_mul_f32 %0, %1, %2 op_sel:[1,0] op_sel_hi:[0,1] neg_lo:[1,0]"
              : "=v"(r) : "v"(d), "v"(ss)); return r;
}

// Issue all global loads for one t-row chunk into regs R[], ds addrs into DS[].
#define STAGE_LOAD(R, DS, NT, CE_, NIT, T0)                                \
    _Pragma("unroll")                                                      \
    for (int i = 0; i < NIT; ++i) {                                        \
        const int e = lane + i * 64;                                       \
        f2 v = (f2){0.f, 0.f};                                             \
        int da = 0;                                                        \
        if (e < (CE_)) {                                                   \
            const int gq = e / ((NT) * NW), rq = e - gq * ((NT) * NW);     \
            const int tq = rq / NW, wq = rq - tq * NW;                     \
            const int Mq = Mw + gq;                                        \
            da = gq * BUFS + wq * (NT) + tq;                               \
            if (Mq < NM) {                                                 \
                const int nq = Mq >> 4, aq = Mq & 15;                      \
                const int go = (nq * NS + (T0) + tq) * (NA * NW) + aq * NW + wq; \
                v = (f2){x_real[go], x_imag[go]};                          \
            }                                                              \
        }                                                                  \
        R[i] = v; DS[i] = da;                                              \
    }

// Write a register-staged chunk to the wave-private LDS region.
#define STAGE_WRITE(R, DS, CE_, NIT)                                       \
    _Pragma("unroll")                                                      \
    for (int i = 0; i < NIT; ++i) {                                        \
        const int e = lane + i * 64;                                       \
        if (e < (CE_)) wbuf[DS[i]] = R[i];                                 \
    }

// Good-Thomas fused A+B for NT t-rows starting at TBASE, chunk layout
// bp[w*NT + t] (w = true column index 0..32). Per t: 3x DFT-11 (bin j,
// conj-paired, coeffs cb[] = w11^(jb)/sqrt33) then in-register radix-3.
#define COMPUTE_CHUNK(NT, TBASE)                                           \
    if (act) {                                                             \
        const f2* bp = wbuf + gg * BUFS;                                   \
        f2 cb[5];                                                          \
        {                                                                  \
            int m_ = 0;                                                    \
            _Pragma("unroll")                                              \
            for (int b = 1; b <= 5; ++b) {                                 \
                m_ += j; if (m_ >= 11) m_ -= 11;                           \
                cb[b - 1] = sFsub[3 * NW + m_];   /* w11^(j*b)/sqrt33 */   \
            }                                                              \
        }                                                                  \
        _Pragma("unroll")                                                  \
        for (int t = 0; t < (NT); ++t) {                                   \
            f2 Z[3];                                                       \
            _Pragma("unroll")                                              \
            for (int w3 = 0; w3 < 3; ++w3) {                               \
                f2 acc = pkmul(bp[W33[w3][0] * (NT) + t], invs);           \
                _Pragma("unroll")                                          \
                for (int b = 1; b <= 5; ++b) {                             \
                    const f2 xa = bp[W33[w3][b] * (NT) + t];               \
                    const f2 xb = bp[W33[w3][11 - b] * (NT) + t];          \
                    const f2 u = pkadd(xa, xb);                            \
                    const f2 d = pksub(xa, xb);                            \
                    cmac_re(acc, u, cb[b - 1]);                            \
                    cmac_im(acc, d, cb[b - 1]);                            \
                }                                                          \
                Z[w3] = acc;                                               \
            }                                                              \
            /* radix-3 over w3 (raw w3 = (-1/2, -sqrt3/2)):               */ \
            const f2 u2 = pkadd(Z[1], Z[2]);                               \
            const f2 d2 = pksub(Z[1], Z[2]);                               \
            V[(TBASE) + t][0] = pkadd(Z[0], u2);                           \
            const f2 zc = pkfma3(u2, cch, Z[0]);                           \
            const f2 r2 = pkmul_i(d2, ssq);                                \
            V[(TBASE) + t][1] = pkadd(zc, r2);                             \
            V[(TBASE) + t][2] = pksub(zc, r2);                             \
        }                                                                  \
    }

__global__ __launch_bounds__(THREADS, 5) void autocorr_kernel(
    const float* __restrict__ x_real, const float* __restrict__ x_imag,
    const float* __restrict__ Fsym_re, const float* __restrict__ Fsym_im,
    const float* __restrict__ Fsub_re, const float* __restrict__ Fsub_im,
    float* __restrict__ out, int NM, int write_complex)
{
    __shared__ f2 sFsym[NS * NS];     // [s][t]
    __shared__ f2 sFsub[SFS];         // rows 0..16 of symmetric Fsub, row-major
    __shared__ f2 buf[GM * BUFS];     // per-matrix 99: x rows chunk, then T2

    const int tid = threadIdx.x;
    const int wave = tid >> 6;
    const int lane = tid & 63;
    const int Mw = blockIdx.x * GM + wave * MPW;
    f2* const wbuf = &buf[wave * MPW * BUFS];

    // ---- F staging (cooperative): only rows 0..16 of Fsub (561 f2) ----
    for (int i = tid; i < SFS; i += THREADS)
        sFsub[i] = (f2){Fsub_re[i], Fsub_im[i]};
    if (tid < NS * NS) sFsym[tid] = (f2){Fsym_re[tid], Fsym_im[tid]};

    // ---- chunk0 (t=0..2): global->reg->LDS, latency overlaps F staging ----
    {
        f2 rr0[IT0]; int ds0[IT0];
        STAGE_LOAD(rr0, ds0, C0T, C0E, IT0, 0);
        STAGE_WRITE(rr0, ds0, C0E, IT0);
    }
    __syncthreads();   // the ONLY barrier

    const int g = lane / TPM;                 // 0..4 active, 5 for idle lanes
    const int j = lane - g * TPM;
    const bool act = (lane < MPW * TPM);      // 55 of 64 lanes compute
    const int gg = act ? g : 0;
    const int M = Mw + gg;

    // Good-Thomas column set of this thread: Q[k] = (3j + 11k) mod 33.
    int Q[3];
    {
        const int q0 = 3 * j;
        Q[0] = q0;
        int q1 = q0 + 11; if (q1 >= 33) q1 -= 33;
        int q2 = q0 + 22; if (q2 >= 33) q2 -= 33;
        Q[1] = q1; Q[2] = q2;
    }

    // Constants for the FFT stages.
    const float INV33 = 0.17407765595569785f;      // 1/sqrt(33)
    const f2 invs = (f2){INV33, INV33};
    const f2 cch  = (f2){-0.5f, -0.5f};            // Re(w3)
    const f2 ssq  = (f2){-0.8660254037844386f, -0.8660254037844386f}; // Im(w3)

    f2 V[NS][CPT];   // set inside COMPUTE_CHUNK (act lanes)

    COMPUTE_CHUNK(C0T, 0);

    // ---- chunk1 (t=3,4): transient staging; TLP covers the latency.
    //      Overwrites chunk0's region: safe per-wave in-order DS. ----
    {
        f2 rr1[IT1]; int ds1[IT1];
        STAGE_LOAD(rr1, ds1, C1T, C1E, IT1, C0T);
        STAGE_WRITE(rr1, ds1, C1E, IT1);
    }
    asm volatile("s_waitcnt lgkmcnt(0)" ::: "memory");

    COMPUTE_CHUNK(C1T, C0T);

    // ---- Stage C/D: X = F_sym*V (paired); P = |X|^2; T2 (Hermitian p<3) ----
    f2 T2[3][CPT];
#pragma unroll
    for (int p = 0; p < 3; ++p)
#pragma unroll
        for (int k = 0; k < CPT; ++k) T2[p][k] = (f2){0.f, 0.f};
    if (act) {
        // In-place pairing transform: Fsym[s][4]=conj(Fsym[s][1]),
        // Fsym[s][3]=conj(Fsym[s][2]):  V1<-V1+V4, V4<-V1-V4, V2<-V2+V3, V3<-V2-V3
#pragma unroll
        for (int k = 0; k < CPT; ++k) {
            f2 a = V[1][k], b = V[4][k];
            V[1][k] = pkadd(a, b); V[4][k] = pksub(a, b);
            a = V[2][k]; b = V[3][k];
            V[2][k] = pkadd(a, b); V[3][k] = pksub(a, b);
        }
#pragma unroll
        for (int s = 0; s < NS; ++s) {
            const f2 f0 = sFsym[s * NS + 0];   // = 1/sqrt(5), real
            const f2 f1 = sFsym[s * NS + 1];
            const f2 fc2 = sFsym[s * NS + 2];
            f2 X[CPT];
#pragma unroll
            for (int k = 0; k < CPT; ++k) {
                X[k] = pkmul_re(V[0][k], f0);
                cmac_re(X[k], V[1][k], f1); cmac_im(X[k], V[4][k], f1);
                cmac_re(X[k], V[2][k], fc2); cmac_im(X[k], V[3][k], fc2);
            }
#pragma unroll
            for (int k = 0; k < CPT; ++k) {
                const float Pv = X[k].x * X[k].x + X[k].y * X[k].y;
                const f2 Pp = (f2){Pv, Pv};
#pragma unroll
                for (int p = 0; p < 3; ++p)
                    cmacr(T2[p][k], sFsym[s * NS + p], Pp);
            }
        }
        // T2 col-major into the same wave-private region (after all x reads),
        // at the thread's true column indices Q[k].
        f2* const wb = wbuf + gg * BUFS;
#pragma unroll
        for (int k = 0; k < CPT; ++k)
#pragma unroll
            for (int p = 0; p < 3; ++p)
                wb[Q[k] * 3 + p] = T2[p][k];
    }
    asm volatile("s_waitcnt lgkmcnt(0)" ::: "memory");

    // ---- Stage E: Y[p][q] = sum_v T2[p][v]*conj(Fsub[q][v]), q = Q[k] ----
    // Fsub symmetric: F[q][v] = F[v][q] -> read row v, col q (v <= 16 only).
    if (act) {
        const f2* bp = wbuf + gg * BUFS;
        if (!write_complex) {
            // Paired real path: v & 33-v give  su*fr + sd*fi; fold .x+.y at end.
            f2 Ypk[3][CPT];
            {   // v = 0: F[q][0] = 1/sqrt(33) real -> pk_mul init
                f2 fw[CPT];
#pragma unroll
                for (int k = 0; k < CPT; ++k) fw[k] = sFsub[Q[k]];   // row 0
#pragma unroll
                for (int p = 0; p < 3; ++p) {
                    const f2 tc = bp[p];
#pragma unroll
                    for (int k = 0; k < CPT; ++k)
                        Ypk[p][k] = pkmul(tc, fw[k]);
                }
            }
#pragma unroll 4
            for (int vp = 1; vp <= 16; ++vp) {
                const int vq = NW - vp;
                f2 e2[3];
#pragma unroll
                for (int p = 0; p < 3; ++p) {
                    const f2 ta = bp[vp * 3 + p];
                    const f2 tb = bp[vq * 3 + p];
                    e2[p] = pkaddsub(ta, tb);
                }
                f2 fw[CPT];
#pragma unroll
                for (int k = 0; k < CPT; ++k)
                    fw[k] = sFsub[vp * NW + Q[k]];   // = F[Q[k]][vp] by symmetry
#pragma unroll
                for (int p = 0; p < 3; ++p)
#pragma unroll
                    for (int k = 0; k < CPT; ++k)
                        pkfma(Ypk[p][k], e2[p], fw[k]);
            }
            if (M < NM) {
                const int n = M >> 4, a = M & 15;
                const int obase = ((n * NS) * NA + a) * NW;
#pragma unroll
                for (int p = 0; p < 3; ++p) {
                    const int pp = (NS - p) % NS;   // 0,4,3
#pragma unroll
                    for (int k = 0; k < CPT; ++k) {
                        const int q = Q[k];
                        const int qq = (q == 0) ? 0 : (NW - q);
                        const float Yr = Ypk[p][k].x + Ypk[p][k].y;
                        out[obase + p * (NA * NW) + q] = Yr;
                        out[obase + pp * (NA * NW) + qq] = Yr;
                    }
                }
            }
        } else {
            // Fallback: full complex output (not expected on this harness).
            f2 Y[3][CPT];
#pragma unroll
            for (int p = 0; p < 3; ++p)
#pragma unroll
                for (int k = 0; k < CPT; ++k) Y[p][k] = (f2){0.f, 0.f};
            for (int v = 0; v < NW; ++v) {
                const int row = (v <= 16) ? v : (NW - v);
                const float sgn = (v <= 16) ? 1.f : -1.f;   // conj for v>16
                f2 tc[3];
#pragma unroll
                for (int p = 0; p < 3; ++p) tc[p] = bp[v * 3 + p];
                f2 fw[CPT];
#pragma unroll
                for (int k = 0; k < CPT; ++k) {
                    f2 f = sFsub[row * NW + Q[k]];
                    f.y *= sgn;
                    fw[k] = f;
                }
#pragma unroll
                for (int p = 0; p < 3; ++p)
#pragma unroll
                    for (int k = 0; k < CPT; ++k) {
                        Y[p][k].x = fmaf(tc[p].x, fw[k].x, Y[p][k].x);
                        Y[p][k].x = fmaf(tc[p].y, fw[k].y, Y[p][k].x);
                        Y[p][k].y = fmaf(tc[p].y, fw[k].x, Y[p][k].y);
                        Y[p][k].y = fmaf(-tc[p].x, fw[k].y, Y[p][k].y);
                    }
            }
            if (M < NM) {
                const int n = M >> 4, a = M & 15;
#pragma unroll
                for (int p = 0; p < 3; ++p) {
                    const int pp = (NS - p) % NS;
#pragma unroll
                    for (int k = 0; k < CPT; ++k) {
                        const int q = Q[k];
                        const int qq = (q == 0) ? 0 : (NW - q);
                        ((float2*)out)[((n * NS + p) * NA + a) * NW + q] =
                            make_float2(Y[p][k].x, Y[p][k].y);
                        ((float2*)out)[((n * NS + pp) * NA + a) * NW + qq] =
                            make_float2(Y[p][k].x, -Y[p][k].y);
                    }
                }
            }
        }
    }
}

extern "C" void kernel_launch(void* const* d_in, const int* in_sizes, int n_in,
                              void* d_out, int out_size, void* d_ws, size_t ws_size,
                              hipStream_t stream) {
    const float* x_real  = (const float*)d_in[0];
    const float* x_imag  = (const float*)d_in[1];
    const float* Fsym_re = (const float*)d_in[2];
    const float* Fsym_im = (const float*)d_in[3];
    const float* Fsub_re = (const float*)d_in[4];
    const float* Fsub_im = (const float*)d_in[5];

    const int NM = in_sizes[0] / SW;
    const long long n_cplx = (long long)in_sizes[0];
    const int write_complex = ((long long)out_size >= 2 * n_cplx) ? 1 : 0;

    const int blocks = (NM + GM - 1) / GM;

    autocorr_kernel<<<blocks, THREADS, 0, stream>>>(
        x_real, x_imag, Fsym_re, Fsym_im, Fsub_re, Fsub_im,
        (float*)d_out, NM, write_complex);
}